// Round 4
// baseline (226.734 us; speedup 1.0000x reference)
//
#include <hip/hip_runtime.h>

#define NBINS 256
#define NCH 3
#define NHIST (2 * NCH * NBINS)    // 1536 global bins (input + label)
#define HW4 65536                   // 512*512/4 float4s per (batch,channel) plane
#define BLOCKS_PER_JOB 512
#define THREADS 256
#define STEP (2 * NCH * HW4)        // float4 stride between a thread's batches

// ---------------------------------------------------------------------------
// Histogram kernel, atomic-free, pair-shared LDS histograms (32 KB/block ->
// 5 blocks/CU = 20 waves/CU vs 8 before; kernel is latency-bound so occupancy
// is the lever). Lanes (l, l^1) share a 256-bin u8x4-packed histogram:
//   word = wave*2048 + (bin>>2)*32 + (lane>>1)   -> bank = lane>>1 (free 2-way)
// Pair collisions are resolved in-register via DPP partner exchange with a
// SYMMETRIC rule: each lane (after intra-lane merge) adds its partner's
// increments for matching words, so both lanes write identical totals to a
// shared word and the same-instr write race is benign; for multi-slot cases
// the last write in slot order (program order, in-order LDS pipe) carries the
// full total. Worst-case pair bin count = 2 thr * 16 float4 * 4 = 128 < 255.
// ---------------------------------------------------------------------------
__device__ __forceinline__ int dppswap(int v) {
    // quad_perm [1,0,3,2]: swap lanes l <-> l^1
    return __builtin_amdgcn_mov_dpp(v, 0xB1, 0xF, 0xF, false);
}

__device__ __forceinline__ void process4(unsigned int* __restrict__ base, float4 v) {
    const int b0 = (int)fminf(fmaxf(v.x, 0.f), 255.f);  // trunc==floor, v>=0
    const int b1 = (int)fminf(fmaxf(v.y, 0.f), 255.f);
    const int b2 = (int)fminf(fmaxf(v.z, 0.f), 255.f);
    const int b3 = (int)fminf(fmaxf(v.w, 0.f), 255.f);
    const int w0 = b0 >> 2, w1 = b1 >> 2, w2 = b2 >> 2, w3 = b3 >> 2;
    unsigned int i0 = 1u << ((b0 & 3) << 3);
    unsigned int i1 = 1u << ((b1 & 3) << 3);
    unsigned int i2 = 1u << ((b2 & 3) << 3);
    unsigned int i3 = 1u << ((b3 & 3) << 3);
    unsigned int* const p0 = base + w0 * 32;
    unsigned int* const p1 = base + w1 * 32;
    unsigned int* const p2 = base + w2 * 32;
    unsigned int* const p3 = base + w3 * 32;
    // reads first (latency overlaps the VALU merge below)
    const unsigned int r0 = *p0;
    const unsigned int r1 = *p1;
    const unsigned int r2 = *p2;
    const unsigned int r3 = *p3;
    // intra-lane duplicate merge (absorb into the higher slot)
    if (w0 == w1) { i1 += i0; i0 = 0; }
    if (w0 == w2) { i2 += i0; i0 = 0; }
    if (w0 == w3) { i3 += i0; i0 = 0; }
    if (w1 == w2) { i2 += i1; i1 = 0; }
    if (w1 == w3) { i3 += i1; i1 = 0; }
    if (w2 == w3) { i3 += i2; i2 = 0; }
    // partner exchange (lane^1) — post-merge increments, raw words
    const int pw0 = dppswap(w0), pw1 = dppswap(w1);
    const int pw2 = dppswap(w2), pw3 = dppswap(w3);
    const unsigned pi0 = (unsigned)dppswap((int)i0);
    const unsigned pi1 = (unsigned)dppswap((int)i1);
    const unsigned pi2 = (unsigned)dppswap((int)i2);
    const unsigned pi3 = (unsigned)dppswap((int)i3);
    // symmetric cross-merge: absorb partner's matching increments
    i0 += (w0 == pw0 ? pi0 : 0u) + (w0 == pw1 ? pi1 : 0u)
        + (w0 == pw2 ? pi2 : 0u) + (w0 == pw3 ? pi3 : 0u);
    i1 += (w1 == pw0 ? pi0 : 0u) + (w1 == pw1 ? pi1 : 0u)
        + (w1 == pw2 ? pi2 : 0u) + (w1 == pw3 ? pi3 : 0u);
    i2 += (w2 == pw0 ? pi0 : 0u) + (w2 == pw1 ? pi1 : 0u)
        + (w2 == pw2 ? pi2 : 0u) + (w2 == pw3 ? pi3 : 0u);
    i3 += (w3 == pw0 ? pi0 : 0u) + (w3 == pw1 ? pi1 : 0u)
        + (w3 == pw2 ? pi2 : 0u) + (w3 == pw3 ? pi3 : 0u);
    // writes in slot order (program order == LDS pipe order per wave)
    *p0 = r0 + i0;
    *p1 = r1 + i1;
    *p2 = r2 + i2;
    *p3 = r3 + i3;
}

__global__ __launch_bounds__(THREADS, 5) void hist_kernel(
    const float* __restrict__ a, const float* __restrict__ b,
    unsigned int* __restrict__ gh) {
    __shared__ unsigned int sh[8192];  // 32 KB: 4 waves * 64 grp * 32 pairs
    const int tid  = threadIdx.x;
    const int wave = tid >> 6;
    const int lane = tid & 63;

    uint4* shv = (uint4*)sh;
    #pragma unroll
    for (int i = 0; i < 8; ++i)
        shv[tid + i * THREADS] = make_uint4(0u, 0u, 0u, 0u);
    __syncthreads();

    const int job = blockIdx.x / BLOCKS_PER_JOB;   // 0..5
    const int bij = blockIdx.x % BLOCKS_PER_JOB;
    const int arr = job / NCH;   // 0 = input, 1 = label
    const int ch  = job % NCH;

    const float4* __restrict__ src4 = (const float4*)(arr ? b : a);
    unsigned int* const base = &sh[wave * 2048 + (lane >> 1)];

    const unsigned tg  = ((unsigned)bij << 8) | (unsigned)tid;  // 0..131071
    const unsigned hi  = tg >> 16;                               // 0 or 1
    const unsigned pos = tg & (HW4 - 1);
    // thread's batches: bt = 2k + hi, k = 0..15
    const unsigned base_idx = hi * (NCH * HW4) + (unsigned)ch * HW4 + pos;

    // 4 groups of 4 float4s, register double-buffered
    float4 c0 = src4[base_idx + 0u * STEP];
    float4 c1 = src4[base_idx + 1u * STEP];
    float4 c2 = src4[base_idx + 2u * STEP];
    float4 c3 = src4[base_idx + 3u * STEP];
    #pragma unroll
    for (int g2 = 0; g2 < 4; ++g2) {
        float4 n0, n1, n2, n3;
        if (g2 < 3) {
            const unsigned k = (unsigned)(4 * g2 + 4);
            n0 = src4[base_idx + (k + 0u) * STEP];
            n1 = src4[base_idx + (k + 1u) * STEP];
            n2 = src4[base_idx + (k + 2u) * STEP];
            n3 = src4[base_idx + (k + 3u) * STEP];
        }
        process4(base, c0);
        process4(base, c1);
        process4(base, c2);
        process4(base, c3);
        if (g2 < 3) { c0 = n0; c1 = n1; c2 = n2; c3 = n3; }
    }
    __syncthreads();

    // ---- Flush phase 1: wave w reduces ITS region; lane l owns grp g = l.
    // Packed u16x2 accumulate: lo holds bytes 0,2; hiS holds bytes 1,3.
    // Max per u16 slot: 32 pairs * 128 = 4096 < 65535.
    {
        const unsigned int* rbase = &sh[wave * 2048 + lane * 32];
        unsigned lo = 0u, hiS = 0u;
        #pragma unroll
        for (int c = 0; c < 8; ++c) {
            const int cc = (c + lane) & 7;   // bank swizzle for b128 reads
            const uint4 q = *(const uint4*)(rbase + cc * 4);
            lo  += (q.x & 0x00FF00FFu) + (q.y & 0x00FF00FFu)
                 + (q.z & 0x00FF00FFu) + (q.w & 0x00FF00FFu);
            hiS += ((q.x >> 8) & 0x00FF00FFu) + ((q.y >> 8) & 0x00FF00FFu)
                 + ((q.z >> 8) & 0x00FF00FFu) + ((q.w >> 8) & 0x00FF00FFu);
        }
        // scratch into own region (all reads above precede these in-order)
        sh[wave * 2048 + lane]      = lo;    // words 0..63
        sh[wave * 2048 + 64 + lane] = hiS;   // words 64..127
    }
    __syncthreads();

    // ---- Flush phase 2: thread t owns bin t; combine 4 wave-regions.
    {
        const int g = tid >> 2, byte = tid & 3;
        const int off = (byte & 1) ? 64 : 0;
        unsigned s = 0u;
        #pragma unroll
        for (int q = 0; q < 4; ++q) {
            const unsigned v = sh[q * 2048 + off + g];
            s += (byte & 2) ? (v >> 16) : (v & 0xFFFFu);
        }
        atomicAdd(&gh[(arr * NCH + ch) * NBINS + tid], s);
    }
}

// ---------------------------------------------------------------------------
// Final Bhattacharyya kernel: 1 block x 256 threads, fp64 reduction.
// ---------------------------------------------------------------------------
__device__ __forceinline__ double block_reduce256(double v, double* sh4) {
    const int t = threadIdx.x;
    const int lane = t & 63, w = t >> 6;
    #pragma unroll
    for (int o = 32; o > 0; o >>= 1) v += __shfl_down(v, o, 64);
    if (lane == 0) sh4[w] = v;
    __syncthreads();
    double r = sh4[0] + sh4[1] + sh4[2] + sh4[3];
    __syncthreads();
    return r;
}

__global__ __launch_bounds__(256) void bhat_kernel(
    const unsigned int* __restrict__ gh, float* __restrict__ out) {
    __shared__ double sh4[4];
    const int t = threadIdx.x;  // bin index
    double result = 0.0;
    #pragma unroll
    for (int ch = 0; ch < NCH; ++ch) {
        const double h1 = (double)gh[ch * NBINS + t];
        const double h2 = (double)gh[(NCH + ch) * NBINS + t];
        const double s  = block_reduce256(sqrt(h1 * h2), sh4);
        const double s1 = block_reduce256(h1, sh4);
        const double s2 = block_reduce256(h2, sh4);
        const double denom = sqrt((s1 / (double)NBINS) * (s2 / (double)NBINS)) * (double)NBINS;
        const double v = 1.0 - s / denom;
        result += sqrt(v > 0.0 ? v : 0.0);
    }
    if (t == 0) out[0] = (float)result;
}

extern "C" void kernel_launch(void* const* d_in, const int* in_sizes, int n_in,
                              void* d_out, int out_size, void* d_ws, size_t ws_size,
                              hipStream_t stream) {
    const float* input = (const float*)d_in[0];
    const float* label = (const float*)d_in[1];
    float* out = (float*)d_out;
    unsigned int* gh = (unsigned int*)d_ws;

    // d_ws is poisoned with 0xAA before every timed launch — zero the hists.
    hipMemsetAsync(gh, 0, NHIST * sizeof(unsigned int), stream);

    hist_kernel<<<6 * BLOCKS_PER_JOB, THREADS, 0, stream>>>(input, label, gh);
    bhat_kernel<<<1, 256, 0, stream>>>(gh, out);
}